// Round 1
// baseline (1292.473 us; speedup 1.0000x reference)
//
#include <hip/hip_runtime.h>

// Problem constants
#define NN 16
#define CC 128
#define TT 128
#define VV 25
#define KK 3
#define HH 8
#define OCC 256
#define GG 24          // K*H
#define NT 2048        // N*T
#define NTV 51200.0f   // N*T*V

// Workspace layout (float offsets)
#define OFF_BNA   0            // 24*25*25 = 15000
#define OFF_RESWT 15104        // 128*256 = 32768
#define OFF_BSUM  47872        // 256
#define OFF_STATS 48128        // 4*256 = 1024 (main_sum, main_sq, res_sum, res_sq)
#define OFF_PART  49152        // 2048*1024
#define BYTE_MAIN 8585216ull   // (49152+2097152)*4
#define BYTE_RES  42139648ull  // BYTE_MAIN + 2048*256*32*2

#define XS_STRIDE 28           // padded row stride (16B aligned rows)

__device__ __forceinline__ unsigned short f2bf(float f) {
    unsigned u = __float_as_uint(f);
    unsigned r = (u + 0x7fffu + ((u >> 16) & 1u)) >> 16;
    return (unsigned short)r;
}
__device__ __forceinline__ float bf2f(unsigned s) {
    return __uint_as_float(s << 16);
}

__device__ __forceinline__ void store_bf16_32(unsigned short* dst, const float* a) {
    unsigned pk[16];
#pragma unroll
    for (int q = 0; q < 16; q++) {
        float lo = (2*q   < 25) ? a[2*q]   : 0.f;
        float hi = (2*q+1 < 25) ? a[2*q+1] : 0.f;
        pk[q] = (unsigned)f2bf(lo) | ((unsigned)f2bf(hi) << 16);
    }
    uint4* d4 = (uint4*)dst;
    d4[0] = make_uint4(pk[0],pk[1],pk[2],pk[3]);
    d4[1] = make_uint4(pk[4],pk[5],pk[6],pk[7]);
    d4[2] = make_uint4(pk[8],pk[9],pk[10],pk[11]);
    d4[3] = make_uint4(pk[12],pk[13],pk[14],pk[15]);
}

// K1: precompute BnA, bsum, res_w transpose, zero stats
__global__ __launch_bounds__(256) void k_prep(const int* __restrict__ hop,
                                              const float* __restrict__ emb,
                                              const float* __restrict__ A,
                                              const float* __restrict__ b_block,
                                              const float* __restrict__ res_w,
                                              float* __restrict__ ws) {
    int g = blockIdx.x, tid = threadIdx.x;
    if (g < 24) {
        if (tid < 25) {
            int w = tid;
            float nb = 0.f, na = 0.f;
            for (int v = 0; v < 25; v++) {
                float e = emb[g*12 + hop[v*25 + w]];
                nb += e*e;
                float a = A[((size_t)g*25 + v)*25 + w];
                na += a*a;
            }
            nb = sqrtf(nb) + 1e-4f;
            na = sqrtf(na) + 1e-4f;
            for (int v = 0; v < 25; v++) {
                float e = emb[g*12 + hop[v*25 + w]];
                float a = A[((size_t)g*25 + v)*25 + w];
                ws[OFF_BNA + ((size_t)g*25 + v)*25 + w] = e/nb + a/na;
            }
        }
    } else if (g == 24) {
        ws[OFF_BSUM + tid] = b_block[tid] + b_block[256 + tid] + b_block[512 + tid];
        ws[OFF_STATS + tid]       = 0.f;
        ws[OFF_STATS + 256 + tid] = 0.f;
        ws[OFF_STATS + 512 + tid] = 0.f;
        ws[OFF_STATS + 768 + tid] = 0.f;
    } else if (g >= 32) {
        int idx0 = (g - 32) * 1024 + tid;
#pragma unroll
        for (int i = 0; i < 4; i++) {
            int idx = idx0 + i*256;
            int c = idx >> 8, oc = idx & 255;
            ws[OFF_RESWT + c*256 + oc] = res_w[oc*128 + c];
        }
    }
}

// K2: per (n,t): y = x*BnA (LDS), main = y*wg + bsum, res = x*res_w^T + res_b.
// Writes bf16 main/res (padded stride 32) + per-block stat partials.
__global__ __launch_bounds__(256) void k_main(const float* __restrict__ x,
                                              const float* __restrict__ w_block,
                                              const float* __restrict__ res_b,
                                              float* __restrict__ ws,
                                              unsigned short* __restrict__ main_bf,
                                              unsigned short* __restrict__ res_bf) {
    __shared__ float xs[128 * XS_STRIDE];   // 14.3 KB
    __shared__ float ys[384 * XS_STRIDE];   // 43.0 KB
    int b = blockIdx.x;
    int n = b >> 7, t = b & 127;
    int tid = threadIdx.x;

    // stage x[n,:,t,:]
    for (int idx = tid; idx < 3200; idx += 256) {
        int c = idx / 25, v = idx - c*25;
        xs[c*XS_STRIDE + v] = x[(((size_t)n*128 + c)*128 + t)*25 + v];
    }
    __syncthreads();

    // ys[g*16+c][w] = sum_v xs[h*16+c][v] * BnA[g][v][w]
    for (int idx = tid; idx < 9600; idx += 256) {
        int w = idx % 25;
        int gc = idx / 25;              // g*16 + c
        int g = gc >> 4;
        int h = g & 7;
        const float* bna = ws + OFF_BNA + (size_t)g*625 + w;
        const float* xr = xs + (h*16 + (gc & 15)) * XS_STRIDE;
        float acc = 0.f;
#pragma unroll
        for (int v = 0; v < 25; v++) acc = fmaf(xr[v], bna[v*25], acc);
        ys[gc*XS_STRIDE + w] = acc;
    }
    __syncthreads();

    int oc = tid;
    int h = oc >> 5, o = oc & 31;
    float bs = ws[OFF_BSUM + oc];
    float rb = res_b[oc];
    float accm[25], accr[25];
#pragma unroll
    for (int w = 0; w < 25; w++) { accm[w] = bs; accr[w] = rb; }

    // main path: sum over k, c'
#pragma unroll
    for (int k = 0; k < 3; k++) {
        int g = k*8 + h;
        const float* wb = w_block + (size_t)(g*32 + o)*16;
        const float* yr = ys + g*16*XS_STRIDE;
#pragma unroll
        for (int c = 0; c < 16; c++) {
            float wm = wb[c];
#pragma unroll
            for (int w = 0; w < 25; w++)
                accm[w] = fmaf(wm, yr[c*XS_STRIDE + w], accm[w]);
        }
    }

    // residual path: sum over full C
    const float* rwt = ws + OFF_RESWT;
    for (int c = 0; c < 128; c++) {
        float wr = rwt[c*256 + oc];
#pragma unroll
        for (int w = 0; w < 25; w++)
            accr[w] = fmaf(wr, xs[c*XS_STRIDE + w], accr[w]);
    }

    // stat partials
    float s1 = 0.f, s2 = 0.f, r1 = 0.f, r2 = 0.f;
#pragma unroll
    for (int w = 0; w < 25; w++) {
        s1 += accm[w]; s2 = fmaf(accm[w], accm[w], s2);
        r1 += accr[w]; r2 = fmaf(accr[w], accr[w], r2);
    }
    float* part = ws + OFF_PART + (size_t)b*1024;
    part[oc]       = s1;
    part[256 + oc] = s2;
    part[512 + oc] = r1;
    part[768 + oc] = r2;

    size_t base = ((size_t)b*256 + oc) * 32;
    store_bf16_32(main_bf + base, accm);
    store_bf16_32(res_bf + base, accr);
}

// K3: reduce partials -> stats
__global__ __launch_bounds__(256) void k_reduce(float* __restrict__ ws) {
    int g = blockIdx.x;
    int s = g & 3;
    int slice = g >> 2;       // 0..7
    int oc = threadIdx.x;
    const float* part = ws + OFF_PART;
    float acc = 0.f;
    int b0 = slice * 256;
    for (int i = 0; i < 256; i++)
        acc += part[(size_t)(b0 + i)*1024 + s*256 + oc];
    atomicAdd(&ws[OFF_STATS + s*256 + oc], acc);
}

// K4: out = relu(BN1(main) + BN2(res))
__global__ __launch_bounds__(256) void k_final(const float* __restrict__ bn_g,
                                               const float* __restrict__ bn_b,
                                               const float* __restrict__ rbn_g,
                                               const float* __restrict__ rbn_b,
                                               const float* __restrict__ ws,
                                               const unsigned short* __restrict__ main_bf,
                                               const unsigned short* __restrict__ res_bf,
                                               float* __restrict__ out) {
    int b = blockIdx.x;
    int n = b >> 7, t = b & 127;
    int oc = threadIdx.x;
    const float inv = 1.f / NTV;
    float s1 = ws[OFF_STATS + oc],       s2 = ws[OFF_STATS + 256 + oc];
    float r1 = ws[OFF_STATS + 512 + oc], r2 = ws[OFF_STATS + 768 + oc];
    float mm = s1*inv, vm = s2*inv - mm*mm;
    float mr = r1*inv, vr = r2*inv - mr*mr;
    float a1 = bn_g[oc]  * rsqrtf(vm + 1e-5f); float c1 = bn_b[oc]  - a1*mm;
    float a2 = rbn_g[oc] * rsqrtf(vr + 1e-5f); float c2 = rbn_b[oc] - a2*mr;

    const uint4* mp = (const uint4*)(main_bf + ((size_t)b*256 + oc)*32);
    const uint4* rp = (const uint4*)(res_bf  + ((size_t)b*256 + oc)*32);
    float m[32], r[32];
#pragma unroll
    for (int q = 0; q < 4; q++) {
        uint4 u = mp[q];
        m[8*q+0] = bf2f(u.x & 0xffff); m[8*q+1] = bf2f(u.x >> 16);
        m[8*q+2] = bf2f(u.y & 0xffff); m[8*q+3] = bf2f(u.y >> 16);
        m[8*q+4] = bf2f(u.z & 0xffff); m[8*q+5] = bf2f(u.z >> 16);
        m[8*q+6] = bf2f(u.w & 0xffff); m[8*q+7] = bf2f(u.w >> 16);
        uint4 v = rp[q];
        r[8*q+0] = bf2f(v.x & 0xffff); r[8*q+1] = bf2f(v.x >> 16);
        r[8*q+2] = bf2f(v.y & 0xffff); r[8*q+3] = bf2f(v.y >> 16);
        r[8*q+4] = bf2f(v.z & 0xffff); r[8*q+5] = bf2f(v.z >> 16);
        r[8*q+6] = bf2f(v.w & 0xffff); r[8*q+7] = bf2f(v.w >> 16);
    }
    float* op = out + ((size_t)(n*256 + oc)*128 + t)*25;
#pragma unroll
    for (int w = 0; w < 25; w++) {
        float val = fmaf(a1, m[w], c1) + fmaf(a2, r[w], c2);
        op[w] = fmaxf(val, 0.f);
    }
}

extern "C" void kernel_launch(void* const* d_in, const int* in_sizes, int n_in,
                              void* d_out, int out_size, void* d_ws, size_t ws_size,
                              hipStream_t stream) {
    const float* x        = (const float*)d_in[0];
    const int*   hop      = (const int*)  d_in[1];
    const float* emb      = (const float*)d_in[2];
    const float* A        = (const float*)d_in[3];
    const float* w_block  = (const float*)d_in[4];
    const float* b_block  = (const float*)d_in[5];
    const float* bn_g     = (const float*)d_in[6];
    const float* bn_b     = (const float*)d_in[7];
    const float* res_w    = (const float*)d_in[8];
    const float* res_b    = (const float*)d_in[9];
    const float* rbn_g    = (const float*)d_in[10];
    const float* rbn_b    = (const float*)d_in[11];
    float* out = (float*)d_out;
    float* ws  = (float*)d_ws;
    unsigned short* main_bf = (unsigned short*)((char*)d_ws + BYTE_MAIN);
    unsigned short* res_bf  = (unsigned short*)((char*)d_ws + BYTE_RES);

    k_prep  <<<64,   256, 0, stream>>>(hop, emb, A, b_block, res_w, ws);
    k_main  <<<2048, 256, 0, stream>>>(x, w_block, res_b, ws, main_bf, res_bf);
    k_reduce<<<32,   256, 0, stream>>>(ws);
    k_final <<<2048, 256, 0, stream>>>(bn_g, bn_b, rbn_g, rbn_b, ws, main_bf, res_bf, out);
}

// Round 2
// 312.609 us; speedup vs baseline: 4.1345x; 4.1345x over previous
//
#include <hip/hip_runtime.h>

// Problem constants
#define NN 16
#define CC 128
#define TT 128
#define VV 25
#define KK 3
#define HH 8
#define OCC 256
#define NT 2048        // N*T
#define NTV 51200.0f   // N*T*V

// Workspace layout (float offsets)
#define OFF_BNA   0            // 24*25*25 = 15000 floats, [k*8+h][v][w]
#define OFF_RESWT 15104        // 128*256 = 32768 (res_w transposed [c][oc])
#define OFF_BSUM  47872        // 256
#define OFF_STATS 48128        // 4*256 (main_sum, main_sq, res_sum, res_sq)
#define OFF_PART  49152        // 2048*1024
#define BYTE_MAIN 8585216ull   // (49152+2097152)*4
#define BYTE_RES  42139648ull  // BYTE_MAIN + 2048*256*32*2

#define XS_STRIDE 28           // padded row stride (rows 16B-aligned)

__device__ __forceinline__ unsigned short f2bf(float f) {
    unsigned u = __float_as_uint(f);
    unsigned r = (u + 0x7fffu + ((u >> 16) & 1u)) >> 16;
    return (unsigned short)r;
}
__device__ __forceinline__ float bf2f(unsigned s) {
    return __uint_as_float(s << 16);
}

__device__ __forceinline__ void store_bf16_32(unsigned short* dst, const float* a) {
    unsigned pk[16];
#pragma unroll
    for (int q = 0; q < 16; q++) {
        float lo = (2*q   < 25) ? a[2*q]   : 0.f;
        float hi = (2*q+1 < 25) ? a[2*q+1] : 0.f;
        pk[q] = (unsigned)f2bf(lo) | ((unsigned)f2bf(hi) << 16);
    }
    uint4* d4 = (uint4*)dst;
    d4[0] = make_uint4(pk[0],pk[1],pk[2],pk[3]);
    d4[1] = make_uint4(pk[4],pk[5],pk[6],pk[7]);
    d4[2] = make_uint4(pk[8],pk[9],pk[10],pk[11]);
    d4[3] = make_uint4(pk[12],pk[13],pk[14],pk[15]);
}

// K1: precompute BnA, bsum, res_w transpose, zero stats
__global__ __launch_bounds__(256) void k_prep(const int* __restrict__ hop,
                                              const float* __restrict__ emb,
                                              const float* __restrict__ A,
                                              const float* __restrict__ b_block,
                                              const float* __restrict__ res_w,
                                              float* __restrict__ ws) {
    int g = blockIdx.x, tid = threadIdx.x;
    if (g < 24) {
        if (tid < 25) {
            int w = tid;
            float nb = 0.f, na = 0.f;
            for (int v = 0; v < 25; v++) {
                float e = emb[g*12 + hop[v*25 + w]];
                nb += e*e;
                float a = A[((size_t)g*25 + v)*25 + w];
                na += a*a;
            }
            nb = sqrtf(nb) + 1e-4f;
            na = sqrtf(na) + 1e-4f;
            for (int v = 0; v < 25; v++) {
                float e = emb[g*12 + hop[v*25 + w]];
                float a = A[((size_t)g*25 + v)*25 + w];
                ws[OFF_BNA + ((size_t)g*25 + v)*25 + w] = e/nb + a/na;
            }
        }
    } else if (g == 24) {
        ws[OFF_BSUM + tid] = b_block[tid] + b_block[256 + tid] + b_block[512 + tid];
        ws[OFF_STATS + tid]       = 0.f;
        ws[OFF_STATS + 256 + tid] = 0.f;
        ws[OFF_STATS + 512 + tid] = 0.f;
        ws[OFF_STATS + 768 + tid] = 0.f;
    } else if (g >= 32) {
        int idx0 = (g - 32) * 1024 + tid;
#pragma unroll
        for (int i = 0; i < 4; i++) {
            int idx = idx0 + i*256;
            int c = idx >> 8, oc = idx & 255;
            ws[OFF_RESWT + c*256 + oc] = res_w[oc*128 + c];
        }
    }
}

// K2a: graph-conv main path. Per (n,t) block; k looped serially with BnA slice in LDS.
// LDS: xs 14336 + bna 20000 + ys 14336 = 48672 B -> 3 blocks/CU.
__global__ __launch_bounds__(256) void k_gc(const float* __restrict__ x,
                                            const float* __restrict__ w_block,
                                            float* __restrict__ ws,
                                            unsigned short* __restrict__ main_bf) {
    __shared__ float xs[128 * XS_STRIDE];
    __shared__ float bna[8 * 625];
    __shared__ float ys[128 * XS_STRIDE];
    int b = blockIdx.x;
    int n = b >> 7, t = b & 127;
    int tid = threadIdx.x;

    // stage x[n,:,t,:]
    for (int idx = tid; idx < 3200; idx += 256) {
        int c = idx / 25, v = idx - c*25;
        xs[c*XS_STRIDE + v] = x[(((size_t)n*128 + c)*128 + t)*25 + v];
    }

    int oc = tid;
    int h = oc >> 5, o = oc & 31;
    float accm[25];
    float bs = ws[OFF_BSUM + oc];
#pragma unroll
    for (int w = 0; w < 25; w++) accm[w] = bs;

    for (int k = 0; k < 3; k++) {
        // stage BnA slice for this k: [h][v][w], 5000 floats contiguous
        for (int idx = tid; idx < 5000; idx += 256)
            bna[idx] = ws[OFF_BNA + k*5000 + idx];
        __syncthreads();

        // ys[row=(h*16+c)][w] = sum_v xs[row][v] * bna[h][v][w]
        for (int idx = tid; idx < 3200; idx += 256) {
            int row = idx / 25, w = idx - row*25;
            int hh = row >> 4;
            const float* xr = xs + row*XS_STRIDE;
            const float* bcol = bna + hh*625 + w;
            float acc = 0.f;
#pragma unroll
            for (int v = 0; v < 25; v++) acc = fmaf(xr[v], bcol[v*25], acc);
            ys[row*XS_STRIDE + w] = acc;
        }
        __syncthreads();

        // accumulate: accm[w] += sum_c ys[h*16+c][w] * wg[k,h,o,c]
        const float4* wb4 = (const float4*)(w_block + (size_t)((k*8 + h)*32 + o)*16);
        float4 wv0 = wb4[0], wv1 = wb4[1], wv2 = wb4[2], wv3 = wb4[3];
        float wc[16] = {wv0.x,wv0.y,wv0.z,wv0.w, wv1.x,wv1.y,wv1.z,wv1.w,
                        wv2.x,wv2.y,wv2.z,wv2.w, wv3.x,wv3.y,wv3.z,wv3.w};
#pragma unroll
        for (int c = 0; c < 16; c++) {
            const float* yr = ys + (h*16 + c)*XS_STRIDE;
            const float4* y4 = (const float4*)yr;
            float wm = wc[c];
#pragma unroll
            for (int q = 0; q < 6; q++) {
                float4 yv = y4[q];
                accm[4*q+0] = fmaf(wm, yv.x, accm[4*q+0]);
                accm[4*q+1] = fmaf(wm, yv.y, accm[4*q+1]);
                accm[4*q+2] = fmaf(wm, yv.z, accm[4*q+2]);
                accm[4*q+3] = fmaf(wm, yv.w, accm[4*q+3]);
            }
            accm[24] = fmaf(wm, yr[24], accm[24]);
        }
        __syncthreads();
    }

    // stat partials
    float s1 = 0.f, s2 = 0.f;
#pragma unroll
    for (int w = 0; w < 25; w++) { s1 += accm[w]; s2 = fmaf(accm[w], accm[w], s2); }
    float* part = ws + OFF_PART + (size_t)b*1024;
    part[oc]       = s1;
    part[256 + oc] = s2;

    store_bf16_32(main_bf + ((size_t)b*256 + oc)*32, accm);
}

// K2b: residual GEMM. Per (n,t) block, thread = oc.
__global__ __launch_bounds__(256) void k_res(const float* __restrict__ x,
                                             const float* __restrict__ res_b,
                                             float* __restrict__ ws,
                                             unsigned short* __restrict__ res_bf) {
    __shared__ float xs[128 * XS_STRIDE];
    int b = blockIdx.x;
    int n = b >> 7, t = b & 127;
    int tid = threadIdx.x;

    for (int idx = tid; idx < 3200; idx += 256) {
        int c = idx / 25, v = idx - c*25;
        xs[c*XS_STRIDE + v] = x[(((size_t)n*128 + c)*128 + t)*25 + v];
    }
    __syncthreads();

    int oc = tid;
    float accr[25];
    float rb = res_b[oc];
#pragma unroll
    for (int w = 0; w < 25; w++) accr[w] = rb;

    const float* rwt = ws + OFF_RESWT;
#pragma unroll 4
    for (int c = 0; c < 128; c++) {
        float wr = rwt[c*256 + oc];
        const float* xr = xs + c*XS_STRIDE;
        const float4* x4 = (const float4*)xr;
#pragma unroll
        for (int q = 0; q < 6; q++) {
            float4 xv = x4[q];
            accr[4*q+0] = fmaf(wr, xv.x, accr[4*q+0]);
            accr[4*q+1] = fmaf(wr, xv.y, accr[4*q+1]);
            accr[4*q+2] = fmaf(wr, xv.z, accr[4*q+2]);
            accr[4*q+3] = fmaf(wr, xv.w, accr[4*q+3]);
        }
        accr[24] = fmaf(wr, xr[24], accr[24]);
    }

    float r1 = 0.f, r2 = 0.f;
#pragma unroll
    for (int w = 0; w < 25; w++) { r1 += accr[w]; r2 = fmaf(accr[w], accr[w], r2); }
    float* part = ws + OFF_PART + (size_t)b*1024;
    part[512 + oc] = r1;
    part[768 + oc] = r2;

    store_bf16_32(res_bf + ((size_t)b*256 + oc)*32, accr);
}

// K3: reduce partials -> stats
__global__ __launch_bounds__(256) void k_reduce(float* __restrict__ ws) {
    int g = blockIdx.x;
    int s = g & 3;
    int slice = g >> 2;       // 0..7
    int oc = threadIdx.x;
    const float* part = ws + OFF_PART;
    float acc = 0.f;
    int b0 = slice * 256;
    for (int i = 0; i < 256; i++)
        acc += part[(size_t)(b0 + i)*1024 + s*256 + oc];
    atomicAdd(&ws[OFF_STATS + s*256 + oc], acc);
}

// K4: out = relu(BN1(main) + BN2(res))
__global__ __launch_bounds__(256) void k_final(const float* __restrict__ bn_g,
                                               const float* __restrict__ bn_b,
                                               const float* __restrict__ rbn_g,
                                               const float* __restrict__ rbn_b,
                                               const float* __restrict__ ws,
                                               const unsigned short* __restrict__ main_bf,
                                               const unsigned short* __restrict__ res_bf,
                                               float* __restrict__ out) {
    int b = blockIdx.x;
    int n = b >> 7, t = b & 127;
    int oc = threadIdx.x;
    const float inv = 1.f / NTV;
    float s1 = ws[OFF_STATS + oc],       s2 = ws[OFF_STATS + 256 + oc];
    float r1 = ws[OFF_STATS + 512 + oc], r2 = ws[OFF_STATS + 768 + oc];
    float mm = s1*inv, vm = s2*inv - mm*mm;
    float mr = r1*inv, vr = r2*inv - mr*mr;
    float a1 = bn_g[oc]  * rsqrtf(vm + 1e-5f); float c1 = bn_b[oc]  - a1*mm;
    float a2 = rbn_g[oc] * rsqrtf(vr + 1e-5f); float c2 = rbn_b[oc] - a2*mr;

    const uint4* mp = (const uint4*)(main_bf + ((size_t)b*256 + oc)*32);
    const uint4* rp = (const uint4*)(res_bf  + ((size_t)b*256 + oc)*32);
    float* op = out + ((size_t)(n*256 + oc)*128 + t)*25;
#pragma unroll
    for (int q = 0; q < 4; q++) {
        uint4 u = mp[q];
        uint4 v = rp[q];
        float m[8], r[8];
        m[0] = bf2f(u.x & 0xffff); m[1] = bf2f(u.x >> 16);
        m[2] = bf2f(u.y & 0xffff); m[3] = bf2f(u.y >> 16);
        m[4] = bf2f(u.z & 0xffff); m[5] = bf2f(u.z >> 16);
        m[6] = bf2f(u.w & 0xffff); m[7] = bf2f(u.w >> 16);
        r[0] = bf2f(v.x & 0xffff); r[1] = bf2f(v.x >> 16);
        r[2] = bf2f(v.y & 0xffff); r[3] = bf2f(v.y >> 16);
        r[4] = bf2f(v.z & 0xffff); r[5] = bf2f(v.z >> 16);
        r[6] = bf2f(v.w & 0xffff); r[7] = bf2f(v.w >> 16);
#pragma unroll
        for (int j = 0; j < 8; j++) {
            int idx = 8*q + j;
            if (idx < 25) {
                float val = fmaf(a1, m[j], c1) + fmaf(a2, r[j], c2);
                op[idx] = fmaxf(val, 0.f);
            }
        }
    }
}

extern "C" void kernel_launch(void* const* d_in, const int* in_sizes, int n_in,
                              void* d_out, int out_size, void* d_ws, size_t ws_size,
                              hipStream_t stream) {
    const float* x        = (const float*)d_in[0];
    const int*   hop      = (const int*)  d_in[1];
    const float* emb      = (const float*)d_in[2];
    const float* A        = (const float*)d_in[3];
    const float* w_block  = (const float*)d_in[4];
    const float* b_block  = (const float*)d_in[5];
    const float* bn_g     = (const float*)d_in[6];
    const float* bn_b     = (const float*)d_in[7];
    const float* res_w    = (const float*)d_in[8];
    const float* res_b    = (const float*)d_in[9];
    const float* rbn_g    = (const float*)d_in[10];
    const float* rbn_b    = (const float*)d_in[11];
    float* out = (float*)d_out;
    float* ws  = (float*)d_ws;
    unsigned short* main_bf = (unsigned short*)((char*)d_ws + BYTE_MAIN);
    unsigned short* res_bf  = (unsigned short*)((char*)d_ws + BYTE_RES);

    k_prep  <<<64,   256, 0, stream>>>(hop, emb, A, b_block, res_w, ws);
    k_gc    <<<2048, 256, 0, stream>>>(x, w_block, ws, main_bf);
    k_res   <<<2048, 256, 0, stream>>>(x, res_b, ws, res_bf);
    k_reduce<<<32,   256, 0, stream>>>(ws);
    k_final <<<2048, 256, 0, stream>>>(bn_g, bn_b, rbn_g, rbn_b, ws, main_bf, res_bf, out);
}

// Round 3
// 297.434 us; speedup vs baseline: 4.3454x; 1.0510x over previous
//
#include <hip/hip_runtime.h>

// Problem constants
#define NN 16
#define CC 128
#define TT 128
#define VV 25
#define KK 3
#define HH 8
#define OCC 256
#define NT 2048        // N*T
#define NTV 51200.0f   // N*T*V

// Workspace layout (float offsets)
#define OFF_BNA   0            // 24*700 padded [g][v][28]
#define OFF_RESWT 16896        // 128*256 (res_w transposed [c][oc])
#define OFF_BSUM  49664        // 256
#define OFF_STATS 49920        // 4*256 (main_sum, main_sq, res_sum, res_sq)
#define OFF_PART  51200        // 2048*1024
#define BYTE_MAIN 8593408ull   // (51200+2097152)*4
#define BYTE_RES  42147840ull  // BYTE_MAIN + 2048*256*32*2

#define XS_STRIDE 28           // padded row stride (rows 16B-aligned)

__device__ __forceinline__ unsigned short f2bf(float f) {
    unsigned u = __float_as_uint(f);
    unsigned r = (u + 0x7fffu + ((u >> 16) & 1u)) >> 16;
    return (unsigned short)r;
}
__device__ __forceinline__ float bf2f(unsigned s) {
    return __uint_as_float(s << 16);
}

__device__ __forceinline__ void store_bf16_32(unsigned short* dst, const float* a) {
    unsigned pk[16];
#pragma unroll
    for (int q = 0; q < 16; q++) {
        float lo = (2*q   < 25) ? a[2*q]   : 0.f;
        float hi = (2*q+1 < 25) ? a[2*q+1] : 0.f;
        pk[q] = (unsigned)f2bf(lo) | ((unsigned)f2bf(hi) << 16);
    }
    uint4* d4 = (uint4*)dst;
    d4[0] = make_uint4(pk[0],pk[1],pk[2],pk[3]);
    d4[1] = make_uint4(pk[4],pk[5],pk[6],pk[7]);
    d4[2] = make_uint4(pk[8],pk[9],pk[10],pk[11]);
    d4[3] = make_uint4(pk[12],pk[13],pk[14],pk[15]);
}

// K1: precompute BnA (padded stride 28), bsum, res_w transpose, zero stats
__global__ __launch_bounds__(256) void k_prep(const int* __restrict__ hop,
                                              const float* __restrict__ emb,
                                              const float* __restrict__ A,
                                              const float* __restrict__ b_block,
                                              const float* __restrict__ res_w,
                                              float* __restrict__ ws) {
    int g = blockIdx.x, tid = threadIdx.x;
    if (g < 24) {
        if (tid < 25) {
            int w = tid;
            float nb = 0.f, na = 0.f;
            for (int v = 0; v < 25; v++) {
                float e = emb[g*12 + hop[v*25 + w]];
                nb += e*e;
                float a = A[((size_t)g*25 + v)*25 + w];
                na += a*a;
            }
            nb = sqrtf(nb) + 1e-4f;
            na = sqrtf(na) + 1e-4f;
            for (int v = 0; v < 25; v++) {
                float e = emb[g*12 + hop[v*25 + w]];
                float a = A[((size_t)g*25 + v)*25 + w];
                ws[OFF_BNA + g*700 + v*28 + w] = e/nb + a/na;
            }
        }
        // zero the pad columns (w=25..27)
        for (int idx = tid; idx < 700; idx += 256) {
            if (idx % 28 >= 25) ws[OFF_BNA + g*700 + idx] = 0.f;
        }
    } else if (g == 24) {
        ws[OFF_BSUM + tid] = b_block[tid] + b_block[256 + tid] + b_block[512 + tid];
        ws[OFF_STATS + tid]       = 0.f;
        ws[OFF_STATS + 256 + tid] = 0.f;
        ws[OFF_STATS + 512 + tid] = 0.f;
        ws[OFF_STATS + 768 + tid] = 0.f;
    } else if (g >= 32) {
        int idx0 = (g - 32) * 1024 + tid;
#pragma unroll
        for (int i = 0; i < 4; i++) {
            int idx = idx0 + i*256;
            int c = idx >> 8, oc = idx & 255;
            ws[OFF_RESWT + c*256 + oc] = res_w[oc*128 + c];
        }
    }
}

// K2a: graph-conv main path. Per (n,t) block; k serial, BnA slice in LDS (padded).
// LDS: xs 14336 + bna 22400 + ys 14336 = 51072 B -> 3 blocks/CU.
__global__ __launch_bounds__(256, 3) void k_gc(const float* __restrict__ x,
                                               const float* __restrict__ w_block,
                                               float* __restrict__ ws,
                                               unsigned short* __restrict__ main_bf) {
    __shared__ float xs[128 * XS_STRIDE];
    __shared__ float bna[8 * 700];      // [hh][v][28]
    __shared__ float ys[128 * XS_STRIDE];
    int b = blockIdx.x;
    int n = b >> 7, t = b & 127;
    int tid = threadIdx.x;

    // stage x[n,:,t,:]
    for (int idx = tid; idx < 3200; idx += 256) {
        int c = idx / 25, v = idx - c*25;
        xs[c*XS_STRIDE + v] = x[(((size_t)n*128 + c)*128 + t)*25 + v];
    }

    int oc = tid;
    int h = oc >> 5, o = oc & 31;
    int r  = tid >> 1;                 // row 0..127 for ys stage
    int p  = tid & 1;                  // v-half
    int hh = r >> 4;
    int v0 = p * 13;
    int vcnt = 13 - p;                 // p0: v 0..12 (13), p1: v 13..24 (12)

    float accm[25];
    float bs = ws[OFF_BSUM + oc];
#pragma unroll
    for (int w = 0; w < 25; w++) accm[w] = bs;

    for (int k = 0; k < 3; k++) {
        // stage padded BnA slice for this k: 5600 floats as float4
        {
            const float4* src = (const float4*)(ws + OFF_BNA + k*5600);
            float4* dst = (float4*)bna;
            for (int idx = tid; idx < 1400; idx += 256) dst[idx] = src[idx];
        }
        __syncthreads();

        // ys[r][w] = sum_v xs[r][v]*bna[hh][v][w]; pair-split over v, shfl combine
        {
            float ya[25];
#pragma unroll
            for (int w = 0; w < 25; w++) ya[w] = 0.f;
            const float* xr = xs + r*XS_STRIDE;
            for (int j = 0; j < vcnt; j++) {
                int v = v0 + j;
                float xv = xr[v];
                const float4* br4 = (const float4*)(bna + hh*700 + v*28);
#pragma unroll
                for (int q = 0; q < 6; q++) {
                    float4 bv = br4[q];
                    ya[4*q+0] = fmaf(xv, bv.x, ya[4*q+0]);
                    ya[4*q+1] = fmaf(xv, bv.y, ya[4*q+1]);
                    ya[4*q+2] = fmaf(xv, bv.z, ya[4*q+2]);
                    ya[4*q+3] = fmaf(xv, bv.w, ya[4*q+3]);
                }
                ya[24] = fmaf(xv, (bna + hh*700 + v*28)[24], ya[24]);
            }
#pragma unroll
            for (int w = 0; w < 25; w++) ya[w] += __shfl_xor(ya[w], 1, 64);
            // both halves hold full sums; write disjoint chunks
            float* yr = ys + r*XS_STRIDE;
            if (p == 0) {
                ((float4*)yr)[0] = make_float4(ya[0], ya[1], ya[2],  ya[3]);
                ((float4*)yr)[1] = make_float4(ya[4], ya[5], ya[6],  ya[7]);
                ((float4*)yr)[2] = make_float4(ya[8], ya[9], ya[10], ya[11]);
            } else {
                ((float4*)yr)[3] = make_float4(ya[12], ya[13], ya[14], ya[15]);
                ((float4*)yr)[4] = make_float4(ya[16], ya[17], ya[18], ya[19]);
                ((float4*)yr)[5] = make_float4(ya[20], ya[21], ya[22], ya[23]);
                yr[24] = ya[24];
            }
        }
        __syncthreads();

        // accm[w] += sum_c ys[h*16+c][w] * wg[k,h,o,c]
        const float4* wb4 = (const float4*)(w_block + (size_t)((k*8 + h)*32 + o)*16);
        float4 wv0 = wb4[0], wv1 = wb4[1], wv2 = wb4[2], wv3 = wb4[3];
        float wc[16] = {wv0.x,wv0.y,wv0.z,wv0.w, wv1.x,wv1.y,wv1.z,wv1.w,
                        wv2.x,wv2.y,wv2.z,wv2.w, wv3.x,wv3.y,wv3.z,wv3.w};
#pragma unroll
        for (int c = 0; c < 16; c++) {
            const float* yr = ys + (h*16 + c)*XS_STRIDE;
            const float4* y4 = (const float4*)yr;
            float wm = wc[c];
#pragma unroll
            for (int q = 0; q < 6; q++) {
                float4 yv = y4[q];
                accm[4*q+0] = fmaf(wm, yv.x, accm[4*q+0]);
                accm[4*q+1] = fmaf(wm, yv.y, accm[4*q+1]);
                accm[4*q+2] = fmaf(wm, yv.z, accm[4*q+2]);
                accm[4*q+3] = fmaf(wm, yv.w, accm[4*q+3]);
            }
            accm[24] = fmaf(wm, yr[24], accm[24]);
        }
        __syncthreads();
    }

    // stat partials
    float s1 = 0.f, s2 = 0.f;
#pragma unroll
    for (int w = 0; w < 25; w++) { s1 += accm[w]; s2 = fmaf(accm[w], accm[w], s2); }
    float* part = ws + OFF_PART + (size_t)b*1024;
    part[oc]       = s1;
    part[256 + oc] = s2;

    store_bf16_32(main_bf + ((size_t)b*256 + oc)*32, accm);
}

// K2b: residual GEMM, register-tiled: thread = 4 oc x 8 w.
__global__ __launch_bounds__(256) void k_res(const float* __restrict__ x,
                                             const float* __restrict__ res_b,
                                             float* __restrict__ ws,
                                             unsigned short* __restrict__ res_bf) {
    __shared__ float xs[128 * XS_STRIDE + 8];   // +8 pad: wg=3 reads w24..31
    int b = blockIdx.x;
    int n = b >> 7, t = b & 127;
    int tid = threadIdx.x;

    for (int idx = tid; idx < 3200; idx += 256) {
        int c = idx / 25, v = idx - c*25;
        xs[c*XS_STRIDE + v] = x[(((size_t)n*128 + c)*128 + t)*25 + v];
    }
    __syncthreads();

    int ocg = tid >> 2;          // 0..63
    int wg  = tid & 3;           // 0..3
    int ocb = ocg * 4;
    int wb  = wg * 8;            // 0,8,16,24

    float acc[4][8];
    float rb0 = res_b[ocb], rb1 = res_b[ocb+1], rb2 = res_b[ocb+2], rb3 = res_b[ocb+3];
#pragma unroll
    for (int j = 0; j < 8; j++) { acc[0][j]=rb0; acc[1][j]=rb1; acc[2][j]=rb2; acc[3][j]=rb3; }

    const float* rwt = ws + OFF_RESWT;
    for (int c = 0; c < 128; c++) {
        const float4* x4 = (const float4*)(xs + c*XS_STRIDE + wb);
        float4 xa = x4[0], xb = x4[1];
        float xw[8] = {xa.x,xa.y,xa.z,xa.w, xb.x,xb.y,xb.z,xb.w};
        float4 wv = *(const float4*)(rwt + c*256 + ocb);
        float wr[4] = {wv.x, wv.y, wv.z, wv.w};
#pragma unroll
        for (int i = 0; i < 4; i++)
#pragma unroll
            for (int j = 0; j < 8; j++)
                acc[i][j] = fmaf(wr[i], xw[j], acc[i][j]);
    }

    // per-oc stats (only valid w), cross-wg reduce via shfl
    float s1[4], s2[4];
#pragma unroll
    for (int i = 0; i < 4; i++) {
        s1[i] = 0.f; s2[i] = 0.f;
#pragma unroll
        for (int j = 0; j < 8; j++) {
            if (wb + j < 25) { s1[i] += acc[i][j]; s2[i] = fmaf(acc[i][j], acc[i][j], s2[i]); }
        }
    }
#pragma unroll
    for (int i = 0; i < 4; i++) {
        s1[i] += __shfl_xor(s1[i], 1, 64); s1[i] += __shfl_xor(s1[i], 2, 64);
        s2[i] += __shfl_xor(s2[i], 1, 64); s2[i] += __shfl_xor(s2[i], 2, 64);
    }
    float* part = ws + OFF_PART + (size_t)b*1024;
    if (wg == 0) {
#pragma unroll
        for (int i = 0; i < 4; i++) {
            part[512 + ocb + i] = s1[i];
            part[768 + ocb + i] = s2[i];
        }
    }

    // bf16 store: each thread writes 8 bf16 (16B) per oc
#pragma unroll
    for (int i = 0; i < 4; i++) {
        unsigned pk[4];
#pragma unroll
        for (int q = 0; q < 4; q++)
            pk[q] = (unsigned)f2bf(acc[i][2*q]) | ((unsigned)f2bf(acc[i][2*q+1]) << 16);
        *(uint4*)(res_bf + ((size_t)b*256 + ocb + i)*32 + wb) = make_uint4(pk[0],pk[1],pk[2],pk[3]);
    }
}

// K3: reduce partials -> stats (256 blocks, 32 b's each)
__global__ __launch_bounds__(256) void k_reduce(float* __restrict__ ws) {
    int g = blockIdx.x;
    int s = g & 3;
    int slice = g >> 2;       // 0..63
    int oc = threadIdx.x;
    const float* part = ws + OFF_PART;
    float acc = 0.f;
    int b0 = slice * 32;
    for (int i = 0; i < 32; i++)
        acc += part[(size_t)(b0 + i)*1024 + s*256 + oc];
    atomicAdd(&ws[OFF_STATS + s*256 + oc], acc);
}

// K4: out = relu(BN1(main) + BN2(res))
__global__ __launch_bounds__(256) void k_final(const float* __restrict__ bn_g,
                                               const float* __restrict__ bn_b,
                                               const float* __restrict__ rbn_g,
                                               const float* __restrict__ rbn_b,
                                               const float* __restrict__ ws,
                                               const unsigned short* __restrict__ main_bf,
                                               const unsigned short* __restrict__ res_bf,
                                               float* __restrict__ out) {
    int b = blockIdx.x;
    int n = b >> 7, t = b & 127;
    int oc = threadIdx.x;
    const float inv = 1.f / NTV;
    float s1 = ws[OFF_STATS + oc],       s2 = ws[OFF_STATS + 256 + oc];
    float r1 = ws[OFF_STATS + 512 + oc], r2 = ws[OFF_STATS + 768 + oc];
    float mm = s1*inv, vm = s2*inv - mm*mm;
    float mr = r1*inv, vr = r2*inv - mr*mr;
    float a1 = bn_g[oc]  * rsqrtf(vm + 1e-5f); float c1 = bn_b[oc]  - a1*mm;
    float a2 = rbn_g[oc] * rsqrtf(vr + 1e-5f); float c2 = rbn_b[oc] - a2*mr;

    const uint4* mp = (const uint4*)(main_bf + ((size_t)b*256 + oc)*32);
    const uint4* rp = (const uint4*)(res_bf  + ((size_t)b*256 + oc)*32);
    float* op = out + ((size_t)(n*256 + oc)*128 + t)*25;
#pragma unroll
    for (int q = 0; q < 4; q++) {
        uint4 u = mp[q];
        uint4 v = rp[q];
        float m[8], r[8];
        m[0] = bf2f(u.x & 0xffff); m[1] = bf2f(u.x >> 16);
        m[2] = bf2f(u.y & 0xffff); m[3] = bf2f(u.y >> 16);
        m[4] = bf2f(u.z & 0xffff); m[5] = bf2f(u.z >> 16);
        m[6] = bf2f(u.w & 0xffff); m[7] = bf2f(u.w >> 16);
        r[0] = bf2f(v.x & 0xffff); r[1] = bf2f(v.x >> 16);
        r[2] = bf2f(v.y & 0xffff); r[3] = bf2f(v.y >> 16);
        r[4] = bf2f(v.z & 0xffff); r[5] = bf2f(v.z >> 16);
        r[6] = bf2f(v.w & 0xffff); r[7] = bf2f(v.w >> 16);
#pragma unroll
        for (int j = 0; j < 8; j++) {
            int idx = 8*q + j;
            if (idx < 25) {
                float val = fmaf(a1, m[j], c1) + fmaf(a2, r[j], c2);
                op[idx] = fmaxf(val, 0.f);
            }
        }
    }
}

extern "C" void kernel_launch(void* const* d_in, const int* in_sizes, int n_in,
                              void* d_out, int out_size, void* d_ws, size_t ws_size,
                              hipStream_t stream) {
    const float* x        = (const float*)d_in[0];
    const int*   hop      = (const int*)  d_in[1];
    const float* emb      = (const float*)d_in[2];
    const float* A        = (const float*)d_in[3];
    const float* w_block  = (const float*)d_in[4];
    const float* b_block  = (const float*)d_in[5];
    const float* bn_g     = (const float*)d_in[6];
    const float* bn_b     = (const float*)d_in[7];
    const float* res_w    = (const float*)d_in[8];
    const float* res_b    = (const float*)d_in[9];
    const float* rbn_g    = (const float*)d_in[10];
    const float* rbn_b    = (const float*)d_in[11];
    float* out = (float*)d_out;
    float* ws  = (float*)d_ws;
    unsigned short* main_bf = (unsigned short*)((char*)d_ws + BYTE_MAIN);
    unsigned short* res_bf  = (unsigned short*)((char*)d_ws + BYTE_RES);

    k_prep  <<<64,   256, 0, stream>>>(hop, emb, A, b_block, res_w, ws);
    k_gc    <<<2048, 256, 0, stream>>>(x, w_block, ws, main_bf);
    k_res   <<<2048, 256, 0, stream>>>(x, res_b, ws, res_bf);
    k_reduce<<<256,  256, 0, stream>>>(ws);
    k_final <<<2048, 256, 0, stream>>>(bn_g, bn_b, rbn_g, rbn_b, ws, main_bf, res_bf, out);
}

// Round 5
// 284.024 us; speedup vs baseline: 4.5506x; 1.0472x over previous
//
#include <hip/hip_runtime.h>
#include <stdint.h>

typedef __attribute__((ext_vector_type(8))) short short8;
typedef __attribute__((ext_vector_type(4))) float f32x4;

// ---- byte offsets into d_ws (total 74,054,656 B; proven ws >= 75.7 MB in R1-R3) ----
#define B_BNA    0ull          // 24*625 fp32            = 60000  -> pad 60416
#define B_STATS  60416ull      // 4*256 fp32             = 4096
#define B_RESW2  64512ull      // 256*128 bf16           = 65536
#define B_PART   130048ull     // 256*1024 fp32          = 1048576
#define B_E2     1178624ull    // 8*8*13*128*32 bf16     = 6815744
#define B_XB     7994368ull    // 2048*3328 bf16         = 13631488
#define B_MAIN   21625856ull   // 2048*256*25 bf16       = 26214400
#define B_RES    47840256ull   // 2048*256*25 bf16       = 26214400  (end 74054656)

#define NTV 51200.0f

__device__ __forceinline__ unsigned short f2bf(float f) {
    unsigned u = __float_as_uint(f);
    return (unsigned short)((u + 0x7fffu + ((u >> 16) & 1u)) >> 16);
}
__device__ __forceinline__ float bf2f(unsigned s) { return __uint_as_float(s << 16); }

// K1: BnA (fp32), zero stats, res_w -> bf16 copy
__global__ __launch_bounds__(256) void k_prep(const int* __restrict__ hop,
                                              const float* __restrict__ emb,
                                              const float* __restrict__ A,
                                              const float* __restrict__ res_w,
                                              float* __restrict__ bna,
                                              float* __restrict__ stats,
                                              unsigned short* __restrict__ resw2) {
    int g = blockIdx.x, tid = threadIdx.x;
    if (g < 24) {
        if (tid < 25) {
            int w = tid;
            float nb = 0.f, na = 0.f;
            for (int v = 0; v < 25; v++) {
                float e = emb[g*12 + hop[v*25 + w]];
                nb += e*e;
                float a = A[((size_t)g*25 + v)*25 + w];
                na += a*a;
            }
            nb = sqrtf(nb) + 1e-4f;
            na = sqrtf(na) + 1e-4f;
            for (int v = 0; v < 25; v++) {
                float e = emb[g*12 + hop[v*25 + w]];
                float a = A[((size_t)g*25 + v)*25 + w];
                bna[g*625 + v*25 + w] = e/nb + a/na;
            }
        }
    } else if (g == 24) {
#pragma unroll
        for (int i = 0; i < 4; i++) stats[i*256 + tid] = 0.f;
    } else {
        // g in [25,33): resw2[idx] = bf16(res_w[idx]), idx = oc*128+c (identity layout)
        int base = (g - 25) * 4096 + tid * 16;
#pragma unroll
        for (int j = 0; j < 16; j++) resw2[base + j] = f2bf(res_w[base + j]);
    }
}

// K2: E2[h][og][kc][n=o*32+w][kk] = sum_k3 wg[k3,h,og*4+o,c] * BnA[k3*8+h][v][w]
//     with k = kc*32+kk = c*25+v (k<400, w<25; else 0). bf16.
__global__ __launch_bounds__(256) void k_prep2(const float* __restrict__ w_block,
                                               const float* __restrict__ bna,
                                               unsigned short* __restrict__ E2) {
    int bid = blockIdx.x;            // = h*8+og
    int h = bid >> 3, og = bid & 7;
    int tid = threadIdx.x;
    for (int e = tid; e < 53248; e += 256) {
        int kc = e >> 12;
        int n  = (e >> 5) & 127;
        int kk = e & 31;
        int k  = kc*32 + kk;
        int o  = n >> 5, w = n & 31;
        float val = 0.f;
        if (k < 400 && w < 25) {
            int c = k / 25, v = k - c*25;
            int oc = h*32 + og*4 + o;
            val = w_block[(0*256 + oc)*16 + c] * bna[(0*8+h)*625 + v*25 + w]
                + w_block[(1*256 + oc)*16 + c] * bna[(1*8+h)*625 + v*25 + w]
                + w_block[(2*256 + oc)*16 + c] * bna[(2*8+h)*625 + v*25 + w];
        }
        E2[(size_t)(bid*13 + kc)*4096 + n*32 + kk] = f2bf(val);
    }
}

// K3: xb[b][h*416 + (c%16)*25 + v] = bf16(x[n,c,t,v]), pads (k in [400,416)) zeroed.
__global__ __launch_bounds__(256) void k_xprep(const float* __restrict__ x,
                                               unsigned short* __restrict__ xb) {
    int b = blockIdx.x;
    int n_ = b >> 7, t_ = b & 127;
    int tid = threadIdx.x;
    unsigned short* row = xb + (size_t)b * 3328;
    for (int idx = tid; idx < 3200; idx += 256) {
        int c = idx / 25, v = idx - c*25;
        float val = x[(((size_t)n_*128 + c)*128 + t_)*25 + v];
        row[(c >> 4)*416 + (c & 15)*25 + v] = f2bf(val);
    }
    if (tid < 128) row[(tid >> 4)*416 + 400 + (tid & 15)] = 0;
}

// K4: main GEMM via MFMA. Grid 1024 = 16 mt x 8 h x 8 og (og fastest).
// C[128m x 128n] = A[128x416] * B[416x128]; n = o*32 + w.
__global__ __launch_bounds__(256) void k_gc(const unsigned short* __restrict__ xb,
                                            const unsigned short* __restrict__ E2,
                                            unsigned short* __restrict__ mainp) {
    __shared__ unsigned short Alds[128*32];
    __shared__ unsigned short Blds[128*32];
    int bid = blockIdx.x;
    int og = bid & 7, h = (bid >> 3) & 7, mt = bid >> 6;
    int tid = threadIdx.x;
    int lane = tid & 63, wave = tid >> 6;
    int wm = wave >> 1, wn = wave & 1;
    int lane15 = lane & 15, quad = lane >> 4;

    int srow = tid >> 1, shalf = tid & 1;
    const size_t abase = (size_t)(mt*128 + srow)*3328 + h*416 + shalf*16;
    const size_t bchunk0 = (size_t)(((h*8 + og)*13))*4096 + tid*16;

    f32x4 acc[4][4] = {};

    for (int kc = 0; kc < 13; kc++) {
        // stage A chunk: [128][32] bf16
        {
            const uint4* s = (const uint4*)(xb + abase + kc*32);
            uint4 a0 = s[0], a1 = s[1];
            *(uint4*)&Alds[srow*32 + shalf*16]     = a0;
            *(uint4*)&Alds[srow*32 + shalf*16 + 8] = a1;
        }
        // stage B chunk: contiguous 8 KB
        {
            const uint4* s = (const uint4*)(E2 + bchunk0 + (size_t)kc*4096);
            uint4 b0 = s[0], b1 = s[1];
            *(uint4*)&Blds[tid*16]     = b0;
            *(uint4*)&Blds[tid*16 + 8] = b1;
        }
        __syncthreads();

        short8 af[4], bf[4];
#pragma unroll
        for (int i = 0; i < 4; i++) {
            af[i] = *(const short8*)&Alds[(wm*64 + i*16 + lane15)*32 + quad*8];
            bf[i] = *(const short8*)&Blds[(wn*64 + i*16 + lane15)*32 + quad*8];
        }
#pragma unroll
        for (int i = 0; i < 4; i++)
#pragma unroll
            for (int j = 0; j < 4; j++)
                acc[i][j] = __builtin_amdgcn_mfma_f32_16x16x32_bf16(af[i], bf[j], acc[i][j], 0, 0, 0);
        __syncthreads();
    }

    // epilogue: n = wn*64 + j*16 + lane15 = o*32 + w  ->  o = wn*2 + (j>>1),
    // w = (j&1)*16 + lane15.  (R4 bug: wn term was dropped.)
#pragma unroll
    for (int j = 0; j < 4; j++) {
        int w = (j & 1)*16 + lane15;
        if (w < 25) {
            int oc = h*32 + og*4 + wn*2 + (j >> 1);
#pragma unroll
            for (int i = 0; i < 4; i++) {
                int mb = mt*128 + wm*64 + i*16 + quad*4;
#pragma unroll
                for (int r = 0; r < 4; r++)
                    mainp[(size_t)((mb + r)*256 + oc)*25 + w] = f2bf(acc[i][j][r]);
            }
        }
    }
}

// K5: residual GEMM via MFMA. Grid 800 = 400 mt x 2 nt. M=(b,v)=51200, K=128, N=256.
__global__ __launch_bounds__(256) void k_res(const float* __restrict__ x,
                                             const unsigned short* __restrict__ resw2,
                                             unsigned short* __restrict__ resp) {
    __shared__ unsigned short Alds[128*32];
    __shared__ unsigned short Blds[128*32];
    int bid = blockIdx.x;
    int nt = bid & 1, mt = bid >> 1;
    int tid = threadIdx.x;
    int lane = tid & 63, wave = tid >> 6;
    int wm = wave >> 1, wn = wave & 1;
    int lane15 = lane & 15, quad = lane >> 4;

    int m2row = tid >> 1, shalf = tid & 1;
    int m2 = mt*128 + m2row;
    int bb = m2 / 25, vv = m2 - bb*25;
    int n_ = bb >> 7, t_ = bb & 127;
    const float* xbase = x + ((size_t)n_*128*128 + t_)*25 + vv;  // + c*3200

    f32x4 acc[4][4] = {};

    for (int kc = 0; kc < 4; kc++) {
        // stage A: convert fp32 x -> bf16, thread covers (m2row, 16 c's)
        {
            unsigned short tmp[16];
            int c0 = kc*32 + shalf*16;
#pragma unroll
            for (int j = 0; j < 16; j++)
                tmp[j] = f2bf(xbase[(size_t)(c0 + j)*3200]);
            unsigned pk[8];
#pragma unroll
            for (int q = 0; q < 8; q++)
                pk[q] = (unsigned)tmp[2*q] | ((unsigned)tmp[2*q+1] << 16);
            *(uint4*)&Alds[m2row*32 + shalf*16]     = make_uint4(pk[0], pk[1], pk[2], pk[3]);
            *(uint4*)&Alds[m2row*32 + shalf*16 + 8] = make_uint4(pk[4], pk[5], pk[6], pk[7]);
        }
        // stage B from resw2[oc][c]
        {
            const uint4* s = (const uint4*)(resw2 + (size_t)(nt*128 + m2row)*128 + kc*32 + shalf*16);
            uint4 b0 = s[0], b1 = s[1];
            *(uint4*)&Blds[m2row*32 + shalf*16]     = b0;
            *(uint4*)&Blds[m2row*32 + shalf*16 + 8] = b1;
        }
        __syncthreads();

        short8 af[4], bf[4];
#pragma unroll
        for (int i = 0; i < 4; i++) {
            af[i] = *(const short8*)&Alds[(wm*64 + i*16 + lane15)*32 + quad*8];
            bf[i] = *(const short8*)&Blds[(wn*64 + i*16 + lane15)*32 + quad*8];
        }
#pragma unroll
        for (int i = 0; i < 4; i++)
#pragma unroll
            for (int j = 0; j < 4; j++)
                acc[i][j] = __builtin_amdgcn_mfma_f32_16x16x32_bf16(af[i], bf[j], acc[i][j], 0, 0, 0);
        __syncthreads();
    }

    // epilogue: resp[(b*256+oc)*25 + v]
#pragma unroll
    for (int j = 0; j < 4; j++) {
        int oc = nt*128 + wn*64 + j*16 + lane15;
#pragma unroll
        for (int i = 0; i < 4; i++) {
            int m2b = mt*128 + wm*64 + i*16 + quad*4;
#pragma unroll
            for (int r = 0; r < 4; r++) {
                int m2e = m2b + r;
                int b = m2e / 25, v = m2e - b*25;
                resp[(size_t)(b*256 + oc)*25 + v] = f2bf(acc[i][j][r]);
            }
        }
    }
}

// K6: stat partials from bf16 buffers. Grid 256 (8 b's each).
__global__ __launch_bounds__(256) void k_stats(const unsigned short* __restrict__ mainp,
                                               const unsigned short* __restrict__ resp,
                                               float* __restrict__ part) {
    int oc = threadIdx.x;
    float s1 = 0.f, s2 = 0.f, r1 = 0.f, r2 = 0.f;
#pragma unroll 2
    for (int i = 0; i < 8; i++) {
        int b = blockIdx.x*8 + i;
        const unsigned short* mr = mainp + (size_t)(b*256 + oc)*25;
        const unsigned short* rr = resp  + (size_t)(b*256 + oc)*25;
#pragma unroll
        for (int w = 0; w < 25; w++) {
            float m = bf2f(mr[w]); s1 += m; s2 = fmaf(m, m, s2);
            float r = bf2f(rr[w]); r1 += r; r2 = fmaf(r, r, r2);
        }
    }
    float* p = part + blockIdx.x*1024;
    p[oc] = s1; p[256 + oc] = s2; p[512 + oc] = r1; p[768 + oc] = r2;
}

// K7: reduce partials -> stats. Grid 32 (4 stats x 8 slices of 32 rows).
__global__ __launch_bounds__(256) void k_reduce(const float* __restrict__ part,
                                                float* __restrict__ stats) {
    int s = blockIdx.x & 3, slice = blockIdx.x >> 2;
    int oc = threadIdx.x;
    float acc = 0.f;
    for (int i = 0; i < 32; i++)
        acc += part[(size_t)(slice*32 + i)*1024 + s*256 + oc];
    atomicAdd(&stats[s*256 + oc], acc);
}

// K8: out = relu(BN1(main) + BN2(res))
__global__ __launch_bounds__(256) void k_final(const float* __restrict__ bn_g,
                                               const float* __restrict__ bn_b,
                                               const float* __restrict__ rbn_g,
                                               const float* __restrict__ rbn_b,
                                               const float* __restrict__ stats,
                                               const unsigned short* __restrict__ mainp,
                                               const unsigned short* __restrict__ resp,
                                               float* __restrict__ out) {
    int b = blockIdx.x;
    int n_ = b >> 7, t_ = b & 127;
    int oc = threadIdx.x;
    const float inv = 1.f / NTV;
    float s1 = stats[oc],       s2 = stats[256 + oc];
    float r1 = stats[512 + oc], r2 = stats[768 + oc];
    float mm = s1*inv, vm = s2*inv - mm*mm;
    float mr = r1*inv, vr = r2*inv - mr*mr;
    float a1 = bn_g[oc]  * rsqrtf(vm + 1e-5f); float c1 = bn_b[oc]  - a1*mm;
    float a2 = rbn_g[oc] * rsqrtf(vr + 1e-5f); float c2 = rbn_b[oc] - a2*mr;

    const unsigned short* mrow = mainp + (size_t)(b*256 + oc)*25;
    const unsigned short* rrow = resp  + (size_t)(b*256 + oc)*25;
    float* op = out + ((size_t)(n_*256 + oc)*128 + t_)*25;
#pragma unroll
    for (int w = 0; w < 25; w++) {
        float val = fmaf(a1, bf2f(mrow[w]), c1) + fmaf(a2, bf2f(rrow[w]), c2);
        op[w] = fmaxf(val, 0.f);
    }
}

extern "C" void kernel_launch(void* const* d_in, const int* in_sizes, int n_in,
                              void* d_out, int out_size, void* d_ws, size_t ws_size,
                              hipStream_t stream) {
    const float* x        = (const float*)d_in[0];
    const int*   hop      = (const int*)  d_in[1];
    const float* emb      = (const float*)d_in[2];
    const float* A        = (const float*)d_in[3];
    const float* w_block  = (const float*)d_in[4];
    // d_in[5] b_block, d_in[9] res_b: per-channel biases cancel under batchnorm.
    const float* bn_g     = (const float*)d_in[6];
    const float* bn_b     = (const float*)d_in[7];
    const float* res_w    = (const float*)d_in[8];
    const float* rbn_g    = (const float*)d_in[10];
    const float* rbn_b    = (const float*)d_in[11];
    float* out = (float*)d_out;

    char* ws = (char*)d_ws;
    float*          bna    = (float*)(ws + B_BNA);
    float*          stats  = (float*)(ws + B_STATS);
    unsigned short* resw2  = (unsigned short*)(ws + B_RESW2);
    float*          part   = (float*)(ws + B_PART);
    unsigned short* E2     = (unsigned short*)(ws + B_E2);
    unsigned short* xb     = (unsigned short*)(ws + B_XB);
    unsigned short* mainp  = (unsigned short*)(ws + B_MAIN);
    unsigned short* resp   = (unsigned short*)(ws + B_RES);

    k_prep  <<<33,   256, 0, stream>>>(hop, emb, A, res_w, bna, stats, resw2);
    k_prep2 <<<64,   256, 0, stream>>>(w_block, bna, E2);
    k_xprep <<<2048, 256, 0, stream>>>(x, xb);
    k_gc    <<<1024, 256, 0, stream>>>(xb, E2, mainp);
    k_res   <<<800,  256, 0, stream>>>(x, resw2, resp);
    k_stats <<<256,  256, 0, stream>>>(mainp, resp, part);
    k_reduce<<<32,   256, 0, stream>>>(part, stats);
    k_final <<<2048, 256, 0, stream>>>(bn_g, bn_b, rbn_g, rbn_b, stats, mainp, resp, out);
}

// Round 6
// 240.835 us; speedup vs baseline: 5.3666x; 1.1793x over previous
//
#include <hip/hip_runtime.h>
#include <stdint.h>

typedef __attribute__((ext_vector_type(8))) short short8;
typedef __attribute__((ext_vector_type(4))) float f32x4;

// ---- byte offsets into d_ws (total 74,054,656 B; proven ws >= 75.7 MB in R1-R3) ----
#define B_BNA    0ull          // 24*625 fp32            = 60000  -> pad 60416
#define B_STATS  60416ull      // 4*256 fp32             = 4096
#define B_RESW2  64512ull      // 256*128 bf16           = 65536
#define B_PART   130048ull     // (unused now)
#define B_E2     1178624ull    // 8*8*13*128*32 bf16     = 6815744
#define B_XB     7994368ull    // 2048*3328 bf16         = 13631488
#define B_MAIN   21625856ull   // 2048*256*25 bf16       = 26214400
#define B_RES    47840256ull   // 2048*256*25 bf16       = 26214400  (end 74054656)

#define NTV 51200.0f

__device__ __forceinline__ unsigned short f2bf(float f) {
    unsigned u = __float_as_uint(f);
    return (unsigned short)((u + 0x7fffu + ((u >> 16) & 1u)) >> 16);
}
__device__ __forceinline__ float bf2f(unsigned s) { return __uint_as_float(s << 16); }

__device__ __forceinline__ float wave_sum(float v) {
#pragma unroll
    for (int m = 1; m < 64; m <<= 1) v += __shfl_xor(v, m, 64);
    return v;
}

// K1: BnA (fp32), zero stats, res_w -> bf16 copy
__global__ __launch_bounds__(256) void k_prep(const int* __restrict__ hop,
                                              const float* __restrict__ emb,
                                              const float* __restrict__ A,
                                              const float* __restrict__ res_w,
                                              float* __restrict__ bna,
                                              float* __restrict__ stats,
                                              unsigned short* __restrict__ resw2) {
    int g = blockIdx.x, tid = threadIdx.x;
    if (g < 24) {
        if (tid < 25) {
            int w = tid;
            float nb = 0.f, na = 0.f;
            for (int v = 0; v < 25; v++) {
                float e = emb[g*12 + hop[v*25 + w]];
                nb += e*e;
                float a = A[((size_t)g*25 + v)*25 + w];
                na += a*a;
            }
            nb = sqrtf(nb) + 1e-4f;
            na = sqrtf(na) + 1e-4f;
            for (int v = 0; v < 25; v++) {
                float e = emb[g*12 + hop[v*25 + w]];
                float a = A[((size_t)g*25 + v)*25 + w];
                bna[g*625 + v*25 + w] = e/nb + a/na;
            }
        }
    } else if (g == 24) {
#pragma unroll
        for (int i = 0; i < 4; i++) stats[i*256 + tid] = 0.f;
    } else {
        // g in [25,33): resw2[idx] = bf16(res_w[idx]), idx = oc*128+c (identity layout)
        int base = (g - 25) * 4096 + tid * 16;
#pragma unroll
        for (int j = 0; j < 16; j++) resw2[base + j] = f2bf(res_w[base + j]);
    }
}

// K2: E2[(h*8+og)*53248 + e], e = kc*4096 + n*32 + kk;
//     value = sum_k3 wg[k3,h,og*4+o,c] * BnA[k3*8+h][v][w], k=kc*32+kk=c*25+v.
//     LDS-staged (R5: 59us latency-bound on scalar global loads -> ~3us).
//     Grid 128 = (h, og, half).
__global__ __launch_bounds__(256) void k_prep2(const float* __restrict__ w_block,
                                               const float* __restrict__ bna,
                                               unsigned short* __restrict__ E2) {
    __shared__ float bl[3*625];
    __shared__ float wl[3*64];
    int bid = blockIdx.x;
    int half = bid & 1, og = (bid >> 1) & 7, h = bid >> 4;
    int tid = threadIdx.x;

    for (int i = tid; i < 1875; i += 256) {
        int k3 = i / 625, j = i - k3*625;
        bl[i] = bna[(k3*8 + h)*625 + j];
    }
    if (tid < 192) {
        int k3 = tid >> 6, o = (tid >> 4) & 3, c = tid & 15;
        wl[tid] = w_block[(k3*256 + h*32 + og*4 + o)*16 + c];
    }
    __syncthreads();

    unsigned short* dst = E2 + (size_t)(h*8 + og)*53248;
    int e0 = half * 26624;
    for (int e = e0 + tid; e < e0 + 26624; e += 256) {
        int kc = e >> 12;
        int n  = (e >> 5) & 127;
        int kk = e & 31;
        int k  = kc*32 + kk;
        int o  = n >> 5, w = n & 31;
        float val = 0.f;
        if (k < 400 && w < 25) {
            int c = k / 25, v = k - c*25;
            val = wl[0*64 + o*16 + c] * bl[0*625 + v*25 + w]
                + wl[1*64 + o*16 + c] * bl[1*625 + v*25 + w]
                + wl[2*64 + o*16 + c] * bl[2*625 + v*25 + w];
        }
        dst[e] = f2bf(val);
    }
}

// K3: xb[b][h*416 + (c%16)*25 + v] = bf16(x[n,c,t,v]), pads (k in [400,416)) zeroed.
__global__ __launch_bounds__(256) void k_xprep(const float* __restrict__ x,
                                               unsigned short* __restrict__ xb) {
    int b = blockIdx.x;
    int n_ = b >> 7, t_ = b & 127;
    int tid = threadIdx.x;
    unsigned short* row = xb + (size_t)b * 3328;
    for (int idx = tid; idx < 3200; idx += 256) {
        int c = idx / 25, v = idx - c*25;
        float val = x[(((size_t)n_*128 + c)*128 + t_)*25 + v];
        row[(c >> 4)*416 + (c & 15)*25 + v] = f2bf(val);
    }
    if (tid < 128) row[(tid >> 4)*416 + 400 + (tid & 15)] = 0;
}

// K4: main GEMM via MFMA. Grid 1024 = 16 mt x 8 h x 8 og (og fastest).
// C[128m x 128n] = A[128x416] * B[416x128]; n = o*32 + w. Stats folded in.
__global__ __launch_bounds__(256) void k_gc(const unsigned short* __restrict__ xb,
                                            const unsigned short* __restrict__ E2,
                                            unsigned short* __restrict__ mainp,
                                            float* __restrict__ stats) {
    __shared__ unsigned short Alds[128*32];
    __shared__ unsigned short Blds[128*32];
    int bid = blockIdx.x;
    int og = bid & 7, h = (bid >> 3) & 7, mt = bid >> 6;
    int tid = threadIdx.x;
    int lane = tid & 63, wave = tid >> 6;
    int wm = wave >> 1, wn = wave & 1;
    int lane15 = lane & 15, quad = lane >> 4;

    int srow = tid >> 1, shalf = tid & 1;
    const size_t abase = (size_t)(mt*128 + srow)*3328 + h*416 + shalf*16;
    const size_t bchunk0 = (size_t)(((h*8 + og)*13))*4096 + tid*16;

    f32x4 acc[4][4] = {};

    for (int kc = 0; kc < 13; kc++) {
        {
            const uint4* s = (const uint4*)(xb + abase + kc*32);
            uint4 a0 = s[0], a1 = s[1];
            *(uint4*)&Alds[srow*32 + shalf*16]     = a0;
            *(uint4*)&Alds[srow*32 + shalf*16 + 8] = a1;
        }
        {
            const uint4* s = (const uint4*)(E2 + bchunk0 + (size_t)kc*4096);
            uint4 b0 = s[0], b1 = s[1];
            *(uint4*)&Blds[tid*16]     = b0;
            *(uint4*)&Blds[tid*16 + 8] = b1;
        }
        __syncthreads();

        short8 af[4], bf[4];
#pragma unroll
        for (int i = 0; i < 4; i++) {
            af[i] = *(const short8*)&Alds[(wm*64 + i*16 + lane15)*32 + quad*8];
            bf[i] = *(const short8*)&Blds[(wn*64 + i*16 + lane15)*32 + quad*8];
        }
#pragma unroll
        for (int i = 0; i < 4; i++)
#pragma unroll
            for (int j = 0; j < 4; j++)
                acc[i][j] = __builtin_amdgcn_mfma_f32_16x16x32_bf16(af[i], bf[j], acc[i][j], 0, 0, 0);
        __syncthreads();
    }

    // epilogue: n = wn*64 + j*16 + lane15 = o*32 + w -> o = wn*2 + (j>>1),
    // w = (j&1)*16 + lane15.
    float s1[2] = {0.f, 0.f}, s2[2] = {0.f, 0.f};
#pragma unroll
    for (int j = 0; j < 4; j++) {
        int w = (j & 1)*16 + lane15;
        int p = j >> 1;
        if (w < 25) {
            int oc = h*32 + og*4 + wn*2 + p;
#pragma unroll
            for (int i = 0; i < 4; i++) {
                int mb = mt*128 + wm*64 + i*16 + quad*4;
#pragma unroll
                for (int r = 0; r < 4; r++) {
                    float val = acc[i][j][r];
                    mainp[(size_t)((mb + r)*256 + oc)*25 + w] = f2bf(val);
                    s1[p] += val;
                    s2[p] = fmaf(val, val, s2[p]);
                }
            }
        }
    }
    // per-wave oc is uniform for each p: reduce across 64 lanes, one atomic each.
#pragma unroll
    for (int p = 0; p < 2; p++) {
        float a = wave_sum(s1[p]);
        float b = wave_sum(s2[p]);
        if (lane == 0) {
            int oc = h*32 + og*4 + wn*2 + p;
            atomicAdd(&stats[oc], a);
            atomicAdd(&stats[256 + oc], b);
        }
    }
}

// K5: residual GEMM via MFMA. Grid 800 = 400 mt x 2 nt. M=(b,v)=51200, K=128, N=256.
// Stats folded in.
__global__ __launch_bounds__(256) void k_res(const float* __restrict__ x,
                                             const unsigned short* __restrict__ resw2,
                                             unsigned short* __restrict__ resp,
                                             float* __restrict__ stats) {
    __shared__ unsigned short Alds[128*32];
    __shared__ unsigned short Blds[128*32];
    int bid = blockIdx.x;
    int nt = bid & 1, mt = bid >> 1;
    int tid = threadIdx.x;
    int lane = tid & 63, wave = tid >> 6;
    int wm = wave >> 1, wn = wave & 1;
    int lane15 = lane & 15, quad = lane >> 4;

    int m2row = tid >> 1, shalf = tid & 1;
    int m2 = mt*128 + m2row;
    int bb = m2 / 25, vv = m2 - bb*25;
    int n_ = bb >> 7, t_ = bb & 127;
    const float* xbase = x + ((size_t)n_*128*128 + t_)*25 + vv;  // + c*3200

    f32x4 acc[4][4] = {};

    for (int kc = 0; kc < 4; kc++) {
        {
            unsigned short tmp[16];
            int c0 = kc*32 + shalf*16;
#pragma unroll
            for (int j = 0; j < 16; j++)
                tmp[j] = f2bf(xbase[(size_t)(c0 + j)*3200]);
            unsigned pk[8];
#pragma unroll
            for (int q = 0; q < 8; q++)
                pk[q] = (unsigned)tmp[2*q] | ((unsigned)tmp[2*q+1] << 16);
            *(uint4*)&Alds[m2row*32 + shalf*16]     = make_uint4(pk[0], pk[1], pk[2], pk[3]);
            *(uint4*)&Alds[m2row*32 + shalf*16 + 8] = make_uint4(pk[4], pk[5], pk[6], pk[7]);
        }
        {
            const uint4* s = (const uint4*)(resw2 + (size_t)(nt*128 + m2row)*128 + kc*32 + shalf*16);
            uint4 b0 = s[0], b1 = s[1];
            *(uint4*)&Blds[m2row*32 + shalf*16]     = b0;
            *(uint4*)&Blds[m2row*32 + shalf*16 + 8] = b1;
        }
        __syncthreads();

        short8 af[4], bf[4];
#pragma unroll
        for (int i = 0; i < 4; i++) {
            af[i] = *(const short8*)&Alds[(wm*64 + i*16 + lane15)*32 + quad*8];
            bf[i] = *(const short8*)&Blds[(wn*64 + i*16 + lane15)*32 + quad*8];
        }
#pragma unroll
        for (int i = 0; i < 4; i++)
#pragma unroll
            for (int j = 0; j < 4; j++)
                acc[i][j] = __builtin_amdgcn_mfma_f32_16x16x32_bf16(af[i], bf[j], acc[i][j], 0, 0, 0);
        __syncthreads();
    }

    // epilogue + per-oc stats (oc = nt*128 + wn*64 + j*16 + lane15)
#pragma unroll
    for (int j = 0; j < 4; j++) {
        int oc = nt*128 + wn*64 + j*16 + lane15;
        float s1 = 0.f, s2 = 0.f;
#pragma unroll
        for (int i = 0; i < 4; i++) {
            int m2b = mt*128 + wm*64 + i*16 + quad*4;
#pragma unroll
            for (int r = 0; r < 4; r++) {
                float val = acc[i][j][r];
                int m2e = m2b + r;
                int b = m2e / 25, v = m2e - b*25;
                resp[(size_t)(b*256 + oc)*25 + v] = f2bf(val);
                s1 += val;
                s2 = fmaf(val, val, s2);
            }
        }
        // reduce across quads (lanes with same lane15): xor 16, 32
        s1 += __shfl_xor(s1, 16, 64); s1 += __shfl_xor(s1, 32, 64);
        s2 += __shfl_xor(s2, 16, 64); s2 += __shfl_xor(s2, 32, 64);
        if (quad == 0) {
            atomicAdd(&stats[512 + oc], s1);
            atomicAdd(&stats[768 + oc], s2);
        }
    }
}

// K6: out = relu(BN1(main) + BN2(res))
__global__ __launch_bounds__(256) void k_final(const float* __restrict__ bn_g,
                                               const float* __restrict__ bn_b,
                                               const float* __restrict__ rbn_g,
                                               const float* __restrict__ rbn_b,
                                               const float* __restrict__ stats,
                                               const unsigned short* __restrict__ mainp,
                                               const unsigned short* __restrict__ resp,
                                               float* __restrict__ out) {
    int b = blockIdx.x;
    int n_ = b >> 7, t_ = b & 127;
    int oc = threadIdx.x;
    const float inv = 1.f / NTV;
    float s1 = stats[oc],       s2 = stats[256 + oc];
    float r1 = stats[512 + oc], r2 = stats[768 + oc];
    float mm = s1*inv, vm = s2*inv - mm*mm;
    float mr = r1*inv, vr = r2*inv - mr*mr;
    float a1 = bn_g[oc]  * rsqrtf(vm + 1e-5f); float c1 = bn_b[oc]  - a1*mm;
    float a2 = rbn_g[oc] * rsqrtf(vr + 1e-5f); float c2 = rbn_b[oc] - a2*mr;

    const unsigned short* mrow = mainp + (size_t)(b*256 + oc)*25;
    const unsigned short* rrow = resp  + (size_t)(b*256 + oc)*25;
    float* op = out + ((size_t)(n_*256 + oc)*128 + t_)*25;
#pragma unroll
    for (int w = 0; w < 25; w++) {
        float val = fmaf(a1, bf2f(mrow[w]), c1) + fmaf(a2, bf2f(rrow[w]), c2);
        op[w] = fmaxf(val, 0.f);
    }
}

extern "C" void kernel_launch(void* const* d_in, const int* in_sizes, int n_in,
                              void* d_out, int out_size, void* d_ws, size_t ws_size,
                              hipStream_t stream) {
    const float* x        = (const float*)d_in[0];
    const int*   hop      = (const int*)  d_in[1];
    const float* emb      = (const float*)d_in[2];
    const float* A        = (const float*)d_in[3];
    const float* w_block  = (const float*)d_in[4];
    // d_in[5] b_block, d_in[9] res_b: per-channel biases cancel under batchnorm.
    const float* bn_g     = (const float*)d_in[6];
    const float* bn_b     = (const float*)d_in[7];
    const float* res_w    = (const float*)d_in[8];
    const float* rbn_g    = (const float*)d_in[10];
    const float* rbn_b    = (const float*)d_in[11];
    float* out = (float*)d_out;

    char* ws = (char*)d_ws;
    float*          bna    = (float*)(ws + B_BNA);
    float*          stats  = (float*)(ws + B_STATS);
    unsigned short* resw2  = (unsigned short*)(ws + B_RESW2);
    unsigned short* E2     = (unsigned short*)(ws + B_E2);
    unsigned short* xb     = (unsigned short*)(ws + B_XB);
    unsigned short* mainp  = (unsigned short*)(ws + B_MAIN);
    unsigned short* resp   = (unsigned short*)(ws + B_RES);

    k_prep  <<<33,   256, 0, stream>>>(hop, emb, A, res_w, bna, stats, resw2);
    k_prep2 <<<128,  256, 0, stream>>>(w_block, bna, E2);
    k_xprep <<<2048, 256, 0, stream>>>(x, xb);
    k_gc    <<<1024, 256, 0, stream>>>(xb, E2, mainp, stats);
    k_res   <<<800,  256, 0, stream>>>(x, resw2, resp, stats);
    k_final <<<2048, 256, 0, stream>>>(bn_g, bn_b, rbn_g, rbn_b, stats, mainp, resp, out);
}